// Round 4
// baseline (317.019 us; speedup 1.0000x reference)
//
#include <hip/hip_runtime.h>
#include <hip/hip_bf16.h>

// MoE expert pool: E=8, D=512, H=2048, M=8192 tokens, top-2 routing.
// gemm1: 8-phase pipelined grouped GEMM (chunk-major LDS, half-tile staging,
// counted vmcnt(8), setprio) -> H1. gemm2: R3-proven 2-phase dbuf 128x128.

#define NEXP 8
#define DIM 512
#define HID 2048
#define MTOK 8192
#define PMAX (2*MTOK)
#define TM1 256
#define MT1 80
#define TM2 128
#define MT2 144
#define NT1 (DIM/64)    // 8 BK-steps in gemm1

typedef __bf16 bf16;
typedef __bf16 bf16x8 __attribute__((ext_vector_type(8)));
typedef float  f32x4  __attribute__((ext_vector_type(4)));

#define WAITVM(N) asm volatile("s_waitcnt vmcnt(" #N ")" ::: "memory")

__device__ __forceinline__ void gload16(const bf16* g, bf16* l) {
  __builtin_amdgcn_global_load_lds(
      (const __attribute__((address_space(1))) void*)g,
      (__attribute__((address_space(3))) void*)l, 16, 0, 0);
}

// ---- fp32 -> bf16 convert (tokens) ----
__global__ __launch_bounds__(256) void k_cvt_x(const float* __restrict__ in,
                                               bf16* __restrict__ out, int n4) {
  int i = blockIdx.x*256 + threadIdx.x;
  if (i >= n4) return;
  float4 v = ((const float4* __restrict__)in)[i];
  bf16 o[4];
  o[0]=(bf16)v.x; o[1]=(bf16)v.y; o[2]=(bf16)v.z; o[3]=(bf16)v.w;
  *(uint2*)&out[(size_t)i*4] = *(uint2*)o;
}

// ---- fp32 [E][R][C] -> bf16 [E][C][R] transpose+convert ----
__global__ __launch_bounds__(256) void k_tcvt2(const float* __restrict__ in0,
                                               const float* __restrict__ in1,
                                               bf16* __restrict__ out0,
                                               bf16* __restrict__ out1, int R, int C) {
  __shared__ __align__(16) bf16 t[64][72];
  const int z = blockIdx.z;
  const int e = z & (NEXP-1);
  const float* __restrict__ pin = ((z < NEXP) ? in0 : in1) + (size_t)e*R*C;
  bf16* __restrict__ pout = ((z < NEXP) ? out0 : out1) + (size_t)e*R*C;
  const int c0 = blockIdx.x*64, r0 = blockIdx.y*64;
  const int tid = threadIdx.x;
  const int rr = tid>>4, cc4 = (tid&15)*4;
#pragma unroll
  for (int i=0;i<4;i++){
    int r = i*16 + rr;
    float4 v = *(const float4*)&pin[(size_t)(r0+r)*C + c0 + cc4];
    t[cc4+0][r]=(bf16)v.x; t[cc4+1][r]=(bf16)v.y;
    t[cc4+2][r]=(bf16)v.z; t[cc4+3][r]=(bf16)v.w;
  }
  __syncthreads();
#pragma unroll
  for (int i=0;i<4;i++){
    int c = i*16 + rr;
    *(uint2*)&pout[(size_t)(c0+c)*R + r0 + cc4] = *(uint2*)&t[c][cc4];
  }
}

// ---- routing: count tokens per expert ----
__global__ __launch_bounds__(256) void k_count(const float* __restrict__ disp,
                                               int* __restrict__ cnt) {
  __shared__ int lc[NEXP];
  int t = threadIdx.x;
  if (t < NEXP) lc[t] = 0;
  __syncthreads();
  int m = blockIdx.x*256 + t;
  float4 d0 = *(const float4*)&disp[(size_t)m*NEXP];
  float4 d1 = *(const float4*)&disp[(size_t)m*NEXP+4];
  if (d0.x>0.f) atomicAdd(&lc[0],1);
  if (d0.y>0.f) atomicAdd(&lc[1],1);
  if (d0.z>0.f) atomicAdd(&lc[2],1);
  if (d0.w>0.f) atomicAdd(&lc[3],1);
  if (d1.x>0.f) atomicAdd(&lc[4],1);
  if (d1.y>0.f) atomicAdd(&lc[5],1);
  if (d1.z>0.f) atomicAdd(&lc[6],1);
  if (d1.w>0.f) atomicAdd(&lc[7],1);
  __syncthreads();
  if (t < NEXP) atomicAdd(&cnt[t], lc[t]);
}

// ---- prefix + two tile lists (TM1=256 for gemm1, TM2=128 for gemm2) ----
__global__ void k_scan(const int* __restrict__ cnt, int* __restrict__ base,
                       int* __restrict__ te1, int* __restrict__ trow1, int* __restrict__ tn1,
                       int* __restrict__ te2, int* __restrict__ trow2, int* __restrict__ tn2) {
  __shared__ int sb[NEXP+1], st1[NEXP+1], st2[NEXP+1], sc[NEXP];
  if (threadIdx.x == 0){
    int b=0, t1=0, t2=0;
    for (int e=0;e<NEXP;e++){
      sb[e]=b; st1[e]=t1; st2[e]=t2; sc[e]=cnt[e]; base[e]=b;
      b += sc[e];
      t1 += (sc[e]+TM1-1)/TM1;
      t2 += (sc[e]+TM2-1)/TM2;
    }
    sb[NEXP]=b; st1[NEXP]=t1; st2[NEXP]=t2;
  }
  __syncthreads();
  for (int idx=threadIdx.x; idx<MT1; idx+=blockDim.x){
    int e=-1;
#pragma unroll
    for (int q=0;q<NEXP;q++) if (idx>=st1[q] && idx<st1[q+1]) e=q;
    if (e>=0){
      int k = idx - st1[e];
      int nr = sc[e] - k*TM1; if (nr>TM1) nr=TM1;
      te1[idx]=e; trow1[idx]=sb[e]+k*TM1; tn1[idx]=nr;
    } else te1[idx]=-1;
  }
  for (int idx=threadIdx.x; idx<MT2; idx+=blockDim.x){
    int e=-1;
#pragma unroll
    for (int q=0;q<NEXP;q++) if (idx>=st2[q] && idx<st2[q+1]) e=q;
    if (e>=0){
      int k = idx - st2[e];
      int nr = sc[e] - k*TM2; if (nr>TM2) nr=TM2;
      te2[idx]=e; trow2[idx]=sb[e]+k*TM2; tn2[idx]=nr;
    } else te2[idx]=-1;
  }
}

// ---- fill slot lists ----
__global__ __launch_bounds__(256) void k_fill(const float* __restrict__ disp,
    const float* __restrict__ comb, const float* __restrict__ scales,
    const int* __restrict__ base, int* __restrict__ fillc,
    int* __restrict__ stok, float* __restrict__ sw) {
  int m = blockIdx.x*256 + threadIdx.x;
#pragma unroll
  for (int e=0;e<NEXP;e++){
    float dv = disp[(size_t)m*NEXP + e];
    if (dv > 0.f) {
      int s = atomicAdd(&fillc[e], 1);
      int g = base[e] + s;
      stok[g] = m;
      sw[g] = comb[(size_t)m*NEXP + e] * scales[e];
    }
  }
}

// ---- GEMM1: 8-phase, BM=256 x BN=128 dual-B, BK=64, chunk-major LDS ----
// LDS layout per buffer: A [8 chunk-cols][256 rows][8 elems]; B [8][128][8].
__global__ __launch_bounds__(512) void k_gemm1(const bf16* __restrict__ Xb,
    const bf16* __restrict__ WgT, const bf16* __restrict__ WvT,
    const int* __restrict__ te, const int* __restrict__ trow, const int* __restrict__ tn,
    const int* __restrict__ stok, bf16* __restrict__ H1) {
  const int tile = blockIdx.y;
  const int e = te[tile];
  if (e < 0) return;
  const int row0 = trow[tile], nrows = tn[tile];
  const int n0 = blockIdx.x*128;
  __shared__ __align__(16) bf16 Abuf[2*16384];   // 64 KB (2 x 256x64)
  __shared__ __align__(16) bf16 Bgbuf[2*8192];   // 32 KB (2 x 128x64)
  __shared__ __align__(16) bf16 Bvbuf[2*8192];   // 32 KB
  const int tid = threadIdx.x, lane = tid&63;
  const int wid = tid>>6, wr = wid>>1, wc = wid&1;   // 4M x 2N waves
  const bf16* __restrict__ wg = WgT + (size_t)e*HID*DIM;  // [H][D] K-contig
  const bf16* __restrict__ wv = WvT + (size_t)e*HID*DIM;

  // per-thread fixed rows for staging
  const int ra = tid & 255;                       // A row slot [0,256)
  const int gra = (ra < nrows) ? (row0 + ra) : row0;
  const bf16* __restrict__ tokp = Xb + (size_t)stok[gra]*DIM;
  const int rbq = tid & 127;                      // B row slot [0,128)
  const bf16* __restrict__ wgrow = wg + (size_t)(n0 + rbq)*DIM;
  const bf16* __restrict__ wvrow = wv + (size_t)(n0 + rbq)*DIM;
  const int qa_hi = tid>>8;                       // 0/1
  const int qb_hi = (tid>>7)&3;                   // 0..3
  const int adst = (tid&192)*8;                   // wave-uniform A dest offset
  const int bdst = (tid&64)*8;                    // wave-uniform B dest offset

#define STAGE1(BI, KT, H) do {                                            \
    _Pragma("unroll")                                                     \
    for (int i_=0;i_<2;i_++){                                             \
      int q_ = 4*(H) + 2*i_ + qa_hi;                                      \
      gload16(tokp + (KT)*64 + q_*8, Abuf + (BI)*16384 + q_*2048 + adst); \
    }                                                                     \
    { int q_ = 4*(H) + qb_hi;                                             \
      gload16(wgrow + (KT)*64 + q_*8, Bgbuf + (BI)*8192 + q_*1024 + bdst);\
      gload16(wvrow + (KT)*64 + q_*8, Bvbuf + (BI)*8192 + q_*1024 + bdst);\
    }                                                                     \
  } while(0)

  f32x4 accg[4][4] = {}, accv[4][4] = {};
  const int rlo = lane&15;
  const int qf_lo = lane>>4;          // 0..3

  // prologue: halves for phases 0,1,2
  STAGE1(0, 0, 0);
  STAGE1(0, 0, 1);
  STAGE1(1, 1, 0);
  WAITVM(8);
  __builtin_amdgcn_s_barrier();
  __builtin_amdgcn_sched_barrier(0);

  for (int kt=0; kt<NT1; ++kt){
    const int bi = kt&1;
#pragma unroll
    for (int ks=0; ks<2; ++ks){
      const int p = kt*2 + ks;
      const int qf = ks*4 + qf_lo;
      const bf16* Ab  = Abuf  + bi*16384 + qf*2048;
      const bf16* Bgb = Bgbuf + bi*8192  + qf*1024;
      const bf16* Bvb = Bvbuf + bi*8192  + qf*1024;
      bf16x8 a[4], bg[4], bv[4];
#pragma unroll
      for (int mi=0; mi<4; mi++)
        a[mi] = *(const bf16x8*)&Ab[(wr*64 + mi*16 + rlo)*8];
#pragma unroll
      for (int ni=0; ni<4; ni++){
        bg[ni] = *(const bf16x8*)&Bgb[(wc*64 + ni*16 + rlo)*8];
        bv[ni] = *(const bf16x8*)&Bvb[(wc*64 + ni*16 + rlo)*8];
      }
      // issue half for phase p+3
      if (p+3 < 2*NT1){
        const int f = p+3, fkt = f>>1, fh = f&1, fbi = fkt&1;
        STAGE1(fbi, fkt, fh);
      }
      __builtin_amdgcn_s_setprio(1);
#pragma unroll
      for (int mi=0; mi<4; mi++)
#pragma unroll
        for (int ni=0; ni<4; ni++){
          accg[mi][ni] = __builtin_amdgcn_mfma_f32_16x16x32_bf16(a[mi], bg[ni], accg[mi][ni], 0,0,0);
          accv[mi][ni] = __builtin_amdgcn_mfma_f32_16x16x32_bf16(a[mi], bv[ni], accv[mi][ni], 0,0,0);
        }
      __builtin_amdgcn_s_setprio(0);
      // drain half for phase p+1; never 0 until tail
      if (p < 2*NT1-3)      { WAITVM(8); }
      else if (p == 2*NT1-3){ WAITVM(4); }
      else if (p == 2*NT1-2){ WAITVM(0); }
      if (p < 2*NT1-1){
        __builtin_amdgcn_s_barrier();
        __builtin_amdgcn_sched_barrier(0);
      }
    }
  }
#undef STAGE1

  const int cb = n0 + wc*64 + (lane&15);
  const int rb = wr*64 + (lane>>4)*4;
#pragma unroll
  for (int mi=0; mi<4; mi++)
#pragma unroll
    for (int j=0; j<4; j++){
      int r = rb + mi*16 + j;
      if (r < nrows){
#pragma unroll
        for (int ni=0; ni<4; ni++){
          float g = accg[mi][ni][j], v = accv[mi][ni][j];
          float ge = 0.5f*g*(1.f + erff(g*0.70710678118654752f));
          H1[(size_t)(row0+r)*HID + cb + ni*16] = (bf16)(ge*v);
        }
      }
    }
}

// ---- GEMM2: out += (H1@Wo)*sw; 128x128, R3-proven dbuf + xor swizzle ----
__global__ __launch_bounds__(256) void k_gemm2(const bf16* __restrict__ H1,
    const bf16* __restrict__ WoT,
    const int* __restrict__ te, const int* __restrict__ trow, const int* __restrict__ tn,
    const int* __restrict__ stok, const float* __restrict__ sw, float* __restrict__ out) {
  const int tile = blockIdx.y;
  const int e = te[tile];
  if (e < 0) return;
  const int row0 = trow[tile], nrows = tn[tile];
  const int n0 = blockIdx.x*128;
  __shared__ __align__(16) bf16 Al[2*TM2*64];
  __shared__ __align__(16) bf16 Bl[2*TM2*64];
  const int tid = threadIdx.x, lane = tid&63;
  const int wr = (tid>>7)&1, wc = (tid>>6)&1;
  const bf16* __restrict__ wo = WoT + (size_t)e*DIM*HID;

  const bf16 *asrc[4], *bsrc[4];
#pragma unroll
  for (int i=0;i<4;i++){
    int c = i*256 + tid;
    int r = c>>3, qs = (c&7) ^ (r&7);
    int ar = (r < nrows) ? (row0 + r) : row0;
    asrc[i] = H1 + (size_t)ar*HID + qs*8;
    bsrc[i] = wo + (size_t)(n0 + r)*HID + qs*8;
  }
  const int wbase = (tid&192)*8;

  auto stage = [&](int bi, int kt){
    const int k0 = kt*64;
#pragma unroll
    for (int i=0;i<4;i++){
      gload16(asrc[i]+k0, Al + bi*TM2*64 + i*2048 + wbase);
      gload16(bsrc[i]+k0, Bl + bi*TM2*64 + i*2048 + wbase);
    }
  };

  f32x4 acc[4][4] = {};
  const int rsw = (lane&7)<<3;
  stage(0, 0);
  for (int kt=0; kt<HID/64; ++kt){
    const int bi = kt&1;
    if (kt+1 < HID/64){ stage(bi^1, kt+1); WAITVM(8); }
    else WAITVM(0);
    __builtin_amdgcn_s_barrier();
    __builtin_amdgcn_sched_barrier(0);
#pragma unroll
    for (int ks=0; ks<2; ks++){
      const int kos = (ks*32 + (lane>>4)*8) ^ rsw;
      bf16x8 a[4], b[4];
#pragma unroll
      for (int ni=0; ni<4; ni++)
        b[ni] = *(const bf16x8*)&Bl[bi*TM2*64 + (wc*64 + ni*16 + (lane&15))*64 + kos];
#pragma unroll
      for (int mi=0; mi<4; mi++)
        a[mi] = *(const bf16x8*)&Al[bi*TM2*64 + (wr*64 + mi*16 + (lane&15))*64 + kos];
#pragma unroll
      for (int mi=0; mi<4; mi++)
#pragma unroll
        for (int ni=0; ni<4; ni++)
          acc[mi][ni] = __builtin_amdgcn_mfma_f32_16x16x32_bf16(a[mi], b[ni], acc[mi][ni], 0,0,0);
    }
    __builtin_amdgcn_s_barrier();
    __builtin_amdgcn_sched_barrier(0);
  }
  const int cb = n0 + wc*64 + (lane&15);
  const int rb = wr*64 + (lane>>4)*4;
#pragma unroll
  for (int mi=0; mi<4; mi++)
#pragma unroll
    for (int j=0; j<4; j++){
      int r = rb + mi*16 + j;
      if (r < nrows){
        int slot = row0 + r;
        float wgt = sw[slot];
        float* op = out + (size_t)stok[slot]*DIM + cb;
#pragma unroll
        for (int ni=0; ni<4; ni++)
          atomicAdd(op + ni*16, acc[mi][ni][j] * wgt);
      }
    }
}

extern "C" void kernel_launch(void* const* d_in, const int* in_sizes, int n_in,
                              void* d_out, int out_size, void* d_ws, size_t ws_size,
                              hipStream_t stream) {
  const float* tokens = (const float*)d_in[0];
  const float* disp   = (const float*)d_in[1];
  const float* comb   = (const float*)d_in[2];
  const float* Wg     = (const float*)d_in[3];
  const float* Wv     = (const float*)d_in[4];
  const float* Wo     = (const float*)d_in[5];
  const float* scales = (const float*)d_in[6];
  float* out = (float*)d_out;

  size_t off = 0;
  char* wsb = (char*)d_ws;
  auto take = [&](size_t bytes)->char* {
    char* q = wsb + off; off += (bytes + 255) & ~(size_t)255; return q;
  };
  int*   cnt   = (int*)  take(NEXP*4);
  int*   basee = (int*)  take(NEXP*4);
  int*   fillc = (int*)  take(NEXP*4);
  int*   te1   = (int*)  take(MT1*4);
  int*   trow1 = (int*)  take(MT1*4);
  int*   tn1   = (int*)  take(MT1*4);
  int*   te2   = (int*)  take(MT2*4);
  int*   trow2 = (int*)  take(MT2*4);
  int*   tn2   = (int*)  take(MT2*4);
  int*   stok  = (int*)  take((size_t)PMAX*4);
  float* sw    = (float*)take((size_t)PMAX*4);
  bf16*  Xb    = (bf16*) take((size_t)MTOK*DIM*2);
  bf16*  WgT   = (bf16*) take((size_t)NEXP*DIM*HID*2);
  bf16*  WvT   = (bf16*) take((size_t)NEXP*DIM*HID*2);
  bf16*  WoT   = (bf16*) take((size_t)NEXP*DIM*HID*2);
  bf16*  H1    = (bf16*) take((size_t)PMAX*HID*2);
  (void)ws_size; (void)in_sizes; (void)n_in;

  hipMemsetAsync(d_ws, 0, 768, stream);
  hipMemsetAsync(d_out, 0, (size_t)out_size*sizeof(float), stream);

  k_cvt_x<<<dim3((MTOK*DIM/4)/256), 256, 0, stream>>>(tokens, Xb, MTOK*DIM/4);
  k_tcvt2<<<dim3(HID/64, DIM/64, 2*NEXP), 256, 0, stream>>>(Wg, Wv, WgT, WvT, DIM, HID);
  k_tcvt2<<<dim3(DIM/64, HID/64, NEXP), 256, 0, stream>>>(Wo, Wo, WoT, WoT, HID, DIM);
  k_count<<<dim3(MTOK/256), 256, 0, stream>>>(disp, cnt);
  k_scan <<<1, 64, 0, stream>>>(cnt, basee, te1, trow1, tn1, te2, trow2, tn2);
  k_fill <<<dim3(MTOK/256), 256, 0, stream>>>(disp, comb, scales, basee, fillc, stok, sw);
  k_gemm1<<<dim3(HID/128, MT1), 512, 0, stream>>>(Xb, WgT, WvT, te1, trow1, tn1, stok, H1);
  k_gemm2<<<dim3(DIM/128, MT2), 256, 0, stream>>>(H1, WoT, te2, trow2, tn2, stok, sw, out);
}

// Round 5
// 267.043 us; speedup vs baseline: 1.1871x; 1.1871x over previous
//
#include <hip/hip_runtime.h>
#include <hip/hip_bf16.h>

// MoE expert pool: E=8, D=512, H=2048, M=8192 tokens, top-2 routing.
// gemm1: 4-phase pipelined template (BM256 x BN128 dual-B interleaved, BK64,
//   coalesced row-major+XOR LDS staging, vmcnt(4)/phase, setprio) -> H1.
// gemm2: R3-proven 2-phase dbuf 128x128 -> gout (plain stores, no atomics).
// k_comb: out[tok] = gout[slot0] + gout[slot1].

#define NEXP 8
#define DIM 512
#define HID 2048
#define MTOK 8192
#define PMAX (2*MTOK)
#define TM1 256
#define MT1 80
#define TM2 128
#define MT2 144

typedef __bf16 bf16;
typedef __bf16 bf16x8 __attribute__((ext_vector_type(8)));
typedef float  f32x4  __attribute__((ext_vector_type(4)));

#define WAITVM(N) asm volatile("s_waitcnt vmcnt(" #N ")" ::: "memory")
#define LGKM0     asm volatile("s_waitcnt lgkmcnt(0)" ::: "memory")
#define SCHED0    __builtin_amdgcn_sched_barrier(0)
#define BAR       __builtin_amdgcn_s_barrier

__device__ __forceinline__ void gload16(const bf16* g, bf16* l) {
  __builtin_amdgcn_global_load_lds(
      (const __attribute__((address_space(1))) void*)g,
      (__attribute__((address_space(3))) void*)l, 16, 0, 0);
}

// ---- fp32 -> bf16 convert (tokens) ----
__global__ __launch_bounds__(256) void k_cvt_x(const float* __restrict__ in,
                                               bf16* __restrict__ out, int n4) {
  int i = blockIdx.x*256 + threadIdx.x;
  if (i >= n4) return;
  float4 v = ((const float4* __restrict__)in)[i];
  bf16 o[4];
  o[0]=(bf16)v.x; o[1]=(bf16)v.y; o[2]=(bf16)v.z; o[3]=(bf16)v.w;
  *(uint2*)&out[(size_t)i*4] = *(uint2*)o;
}

// ---- fp32 [E][R][C] -> bf16 [E][C][R] transpose+convert ----
__global__ __launch_bounds__(256) void k_tcvt2(const float* __restrict__ in0,
                                               const float* __restrict__ in1,
                                               bf16* __restrict__ out0,
                                               bf16* __restrict__ out1, int R, int C) {
  __shared__ __align__(16) bf16 t[64][72];
  const int z = blockIdx.z;
  const int e = z & (NEXP-1);
  const float* __restrict__ pin = ((z < NEXP) ? in0 : in1) + (size_t)e*R*C;
  bf16* __restrict__ pout = ((z < NEXP) ? out0 : out1) + (size_t)e*R*C;
  const int c0 = blockIdx.x*64, r0 = blockIdx.y*64;
  const int tid = threadIdx.x;
  const int rr = tid>>4, cc4 = (tid&15)*4;
#pragma unroll
  for (int i=0;i<4;i++){
    int r = i*16 + rr;
    float4 v = *(const float4*)&pin[(size_t)(r0+r)*C + c0 + cc4];
    t[cc4+0][r]=(bf16)v.x; t[cc4+1][r]=(bf16)v.y;
    t[cc4+2][r]=(bf16)v.z; t[cc4+3][r]=(bf16)v.w;
  }
  __syncthreads();
#pragma unroll
  for (int i=0;i<4;i++){
    int c = i*16 + rr;
    *(uint2*)&pout[(size_t)(c0+c)*R + r0 + cc4] = *(uint2*)&t[c][cc4];
  }
}

// ---- routing: count tokens per expert ----
__global__ __launch_bounds__(256) void k_count(const float* __restrict__ disp,
                                               int* __restrict__ cnt) {
  __shared__ int lc[NEXP];
  int t = threadIdx.x;
  if (t < NEXP) lc[t] = 0;
  __syncthreads();
  int m = blockIdx.x*256 + t;
  float4 d0 = *(const float4*)&disp[(size_t)m*NEXP];
  float4 d1 = *(const float4*)&disp[(size_t)m*NEXP+4];
  if (d0.x>0.f) atomicAdd(&lc[0],1);
  if (d0.y>0.f) atomicAdd(&lc[1],1);
  if (d0.z>0.f) atomicAdd(&lc[2],1);
  if (d0.w>0.f) atomicAdd(&lc[3],1);
  if (d1.x>0.f) atomicAdd(&lc[4],1);
  if (d1.y>0.f) atomicAdd(&lc[5],1);
  if (d1.z>0.f) atomicAdd(&lc[6],1);
  if (d1.w>0.f) atomicAdd(&lc[7],1);
  __syncthreads();
  if (t < NEXP) atomicAdd(&cnt[t], lc[t]);
}

// ---- prefix + two tile lists ----
__global__ void k_scan(const int* __restrict__ cnt, int* __restrict__ base,
                       int* __restrict__ te1, int* __restrict__ trow1, int* __restrict__ tn1,
                       int* __restrict__ te2, int* __restrict__ trow2, int* __restrict__ tn2) {
  __shared__ int sb[NEXP+1], st1[NEXP+1], st2[NEXP+1], sc[NEXP];
  if (threadIdx.x == 0){
    int b=0, t1=0, t2=0;
    for (int e=0;e<NEXP;e++){
      sb[e]=b; st1[e]=t1; st2[e]=t2; sc[e]=cnt[e]; base[e]=b;
      b += sc[e];
      t1 += (sc[e]+TM1-1)/TM1;
      t2 += (sc[e]+TM2-1)/TM2;
    }
    sb[NEXP]=b; st1[NEXP]=t1; st2[NEXP]=t2;
  }
  __syncthreads();
  for (int idx=threadIdx.x; idx<MT1; idx+=blockDim.x){
    int e=-1;
#pragma unroll
    for (int q=0;q<NEXP;q++) if (idx>=st1[q] && idx<st1[q+1]) e=q;
    if (e>=0){
      int k = idx - st1[e];
      int nr = sc[e] - k*TM1; if (nr>TM1) nr=TM1;
      te1[idx]=e; trow1[idx]=sb[e]+k*TM1; tn1[idx]=nr;
    } else te1[idx]=-1;
  }
  for (int idx=threadIdx.x; idx<MT2; idx+=blockDim.x){
    int e=-1;
#pragma unroll
    for (int q=0;q<NEXP;q++) if (idx>=st2[q] && idx<st2[q+1]) e=q;
    if (e>=0){
      int k = idx - st2[e];
      int nr = sc[e] - k*TM2; if (nr>TM2) nr=TM2;
      te2[idx]=e; trow2[idx]=sb[e]+k*TM2; tn2[idx]=nr;
    } else te2[idx]=-1;
  }
}

// ---- fill slot lists + per-token slot map ----
__global__ __launch_bounds__(256) void k_fill(const float* __restrict__ disp,
    const float* __restrict__ comb, const float* __restrict__ scales,
    const int* __restrict__ base, int* __restrict__ fillc,
    int* __restrict__ stok, float* __restrict__ sw, int* __restrict__ sslot) {
  int m = blockIdx.x*256 + threadIdx.x;
  int jj = 0;
#pragma unroll
  for (int e=0;e<NEXP;e++){
    float dv = disp[(size_t)m*NEXP + e];
    if (dv > 0.f) {
      int s = atomicAdd(&fillc[e], 1);
      int g = base[e] + s;
      stok[g] = m;
      sw[g] = comb[(size_t)m*NEXP + e] * scales[e];
      if (jj < 2) sslot[m*2 + jj] = g;
      jj++;
    }
  }
}

// ---- GEMM1: 4-phase template; H1 = gelu(X@Wg)*(X@Wv) ----
// LDS regions: Ab[buf][ht][128x64], Bb[buf][ht][128x64] (ht = consume-half).
// A-ht0 = tile rows {0-63,128-191} (mi0-3 of both wr); ht1 = {64-127,192-255}.
// B rows interleaved: region row r: wc=r>>5, half=(r>>4)&1 (g/v), c=r&15,
//   source col = n0 + wc*32 + ht*16 + c from (half? Wv : Wg).
__global__ __launch_bounds__(512, 2) void k_gemm1(const bf16* __restrict__ Xb,
    const bf16* __restrict__ WgT, const bf16* __restrict__ WvT,
    const int* __restrict__ te, const int* __restrict__ trow, const int* __restrict__ tn,
    const int* __restrict__ stok, bf16* __restrict__ H1) {
  const int tile = blockIdx.y;
  const int e = te[tile];
  if (e < 0) return;
  const int row0 = trow[tile], nrows = tn[tile];
  const int n0 = blockIdx.x*128;
  __shared__ __align__(16) bf16 Ab[2][2][8192];   // 64 KB
  __shared__ __align__(16) bf16 Bb[2][2][8192];   // 64 KB
  const int tid = threadIdx.x, lane = tid&63, wid = tid>>6;
  const int wr = wid>>2, wc = wid&3;              // 2M x 4N waves
  const bf16* __restrict__ wg = WgT + (size_t)e*HID*DIM;  // [H][D] K-contig
  const bf16* __restrict__ wv = WvT + (size_t)e*HID*DIM;

  // staging sources (coalesced: 8 lanes cover one row's 8 chunks, XOR-permuted)
  const bf16 *ap[2][2], *bp[2][2];
#pragma unroll
  for (int ht=0; ht<2; ht++)
#pragma unroll
    for (int i=0;i<2;i++){
      int c = i*512 + tid, lrow = c>>3, q = c&7, qs = q ^ (lrow&7);
      int arow = (lrow&63) + ((lrow>>6)<<7) + ht*64;
      int gr = row0 + ((arow < nrows) ? arow : 0);
      ap[ht][i] = Xb + (size_t)stok[gr]*DIM + qs*8;
      int wcq = lrow>>5, half = (lrow>>4)&1, cc = lrow&15;
      int col = n0 + wcq*32 + ht*16 + cc;
      bp[ht][i] = (half ? wv : wg) + (size_t)col*DIM + qs*8;
    }
  const int dst0 = (tid&448)*8;   // wave-uniform LDS elem offset

#define STA1(BI,HT,KT) { gload16(ap[HT][0]+(KT)*64, &Ab[BI][HT][0]+dst0);      \
                         gload16(ap[HT][1]+(KT)*64, &Ab[BI][HT][0]+4096+dst0); }
#define STB1(BI,HT,KT) { gload16(bp[HT][0]+(KT)*64, &Bb[BI][HT][0]+dst0);      \
                         gload16(bp[HT][1]+(KT)*64, &Bb[BI][HT][0]+4096+dst0); }

  const int r15 = lane&15, kq = lane>>4;
  const int koff0 = ((kq ^ (r15&7)))*8;           // ks0 chunk slot; ks1 = ^32
  const int arowb = wr*64 + r15;
  const int brg = wc*32 + r15, brv = wc*32 + 16 + r15;

#define RDA(D,BI,HT,SMI) { D[0] = *(const bf16x8*)&Ab[BI][HT][(arowb+(SMI)*16)*64 + koff0];        \
                           D[1] = *(const bf16x8*)&Ab[BI][HT][(arowb+(SMI)*16)*64 + (koff0^32)]; }
#define RDB(DG,DV,BI,HT) { DG[0] = *(const bf16x8*)&Bb[BI][HT][brg*64 + koff0];        \
                           DG[1] = *(const bf16x8*)&Bb[BI][HT][brg*64 + (koff0^32)];   \
                           DV[0] = *(const bf16x8*)&Bb[BI][HT][brv*64 + koff0];        \
                           DV[1] = *(const bf16x8*)&Bb[BI][HT][brv*64 + (koff0^32)]; }
#define MM(ACC,A,B) ACC = __builtin_amdgcn_mfma_f32_16x16x32_bf16(A, B, ACC, 0,0,0)

  f32x4 ag[8][2] = {}, av[8][2] = {};
  // prologue: tile 0's ring [A0,B0,A1,B1]
  STA1(0,0,0); STB1(0,0,0); STA1(0,1,0); STB1(0,1,0);
  WAITVM(4); BAR(); SCHED0;

#pragma unroll
  for (int t=0; t<8; ++t){
    const int bi = t&1;
    bf16x8 a[8][2], g0[2], v0[2], g1[2], v1[2];
    // ---- P0: quadrant (mi0-3, ni0) ----
#pragma unroll
    for (int s=0;s<4;s++) RDA(a[s], bi, 0, s);
    RDB(g0, v0, bi, 0);
    if (t<7) STA1(bi^1, 0, t+1);
    BAR(); LGKM0; SCHED0;
    __builtin_amdgcn_s_setprio(1);
#pragma unroll
    for (int mi=0;mi<4;mi++)
#pragma unroll
      for (int ks=0;ks<2;ks++){ MM(ag[mi][0], a[mi][ks], g0[ks]); MM(av[mi][0], a[mi][ks], v0[ks]); }
    __builtin_amdgcn_s_setprio(0);
    if (t<7) { WAITVM(4); } else { WAITVM(2); }
    BAR(); SCHED0;
    // ---- P1: quadrant (mi4-7, ni0) ----
#pragma unroll
    for (int s=0;s<4;s++) RDA(a[4+s], bi, 1, s);
    if (t<7) STB1(bi^1, 0, t+1);
    BAR(); LGKM0; SCHED0;
    __builtin_amdgcn_s_setprio(1);
#pragma unroll
    for (int mi=4;mi<8;mi++)
#pragma unroll
      for (int ks=0;ks<2;ks++){ MM(ag[mi][0], a[mi][ks], g0[ks]); MM(av[mi][0], a[mi][ks], v0[ks]); }
    __builtin_amdgcn_s_setprio(0);
    if (t<7) { WAITVM(4); } else { WAITVM(0); }
    BAR(); SCHED0;
    // ---- P2+P3: (mi0-7, ni1) ----
    RDB(g1, v1, bi, 1);
    if (t<7) { STA1(bi^1, 1, t+1); STB1(bi^1, 1, t+1); }
    BAR(); LGKM0; SCHED0;
    __builtin_amdgcn_s_setprio(1);
#pragma unroll
    for (int mi=0;mi<8;mi++)
#pragma unroll
      for (int ks=0;ks<2;ks++){ MM(ag[mi][1], a[mi][ks], g1[ks]); MM(av[mi][1], a[mi][ks], v1[ks]); }
    __builtin_amdgcn_s_setprio(0);
    if (t<7) { WAITVM(4); BAR(); SCHED0; }
  }
#undef STA1
#undef STB1
#undef RDA
#undef RDB
#undef MM

  const int cb = n0 + wc*32 + r15;
  const int rb = wr*128 + (lane>>4)*4;
#pragma unroll
  for (int mi=0;mi<8;mi++)
#pragma unroll
    for (int j=0;j<4;j++){
      int r = rb + mi*16 + j;
      if (r < nrows){
#pragma unroll
        for (int ni=0;ni<2;ni++){
          float g = ag[mi][ni][j], v = av[mi][ni][j];
          float ge = 0.5f*g*(1.f + erff(g*0.70710678118654752f));
          H1[(size_t)(row0+r)*HID + cb + ni*16] = (bf16)(ge*v);
        }
      }
    }
}

// ---- GEMM2: gout[slot] = (H1@Wo)*sw; 128x128, R3-proven dbuf + xor swizzle ----
__global__ __launch_bounds__(256) void k_gemm2(const bf16* __restrict__ H1,
    const bf16* __restrict__ WoT,
    const int* __restrict__ te, const int* __restrict__ trow, const int* __restrict__ tn,
    const int* __restrict__ stok, const float* __restrict__ sw, float* __restrict__ gout) {
  const int tile = blockIdx.y;
  const int e = te[tile];
  if (e < 0) return;
  const int row0 = trow[tile], nrows = tn[tile];
  const int n0 = blockIdx.x*128;
  __shared__ __align__(16) bf16 Al[2*TM2*64];
  __shared__ __align__(16) bf16 Bl[2*TM2*64];
  const int tid = threadIdx.x, lane = tid&63;
  const int wr = (tid>>7)&1, wc = (tid>>6)&1;
  const bf16* __restrict__ wo = WoT + (size_t)e*DIM*HID;

  const bf16 *asrc[4], *bsrc[4];
#pragma unroll
  for (int i=0;i<4;i++){
    int c = i*256 + tid;
    int r = c>>3, qs = (c&7) ^ (r&7);
    int ar = (r < nrows) ? (row0 + r) : row0;
    asrc[i] = H1 + (size_t)ar*HID + qs*8;
    bsrc[i] = wo + (size_t)(n0 + r)*HID + qs*8;
  }
  const int wbase = (tid&192)*8;

  auto stage = [&](int bi, int kt){
    const int k0 = kt*64;
#pragma unroll
    for (int i=0;i<4;i++){
      gload16(asrc[i]+k0, Al + bi*TM2*64 + i*2048 + wbase);
      gload16(bsrc[i]+k0, Bl + bi*TM2*64 + i*2048 + wbase);
    }
  };

  f32x4 acc[4][4] = {};
  const int rsw = (lane&7)<<3;
  stage(0, 0);
  for (int kt=0; kt<HID/64; ++kt){
    const int bi = kt&1;
    if (kt+1 < HID/64){ stage(bi^1, kt+1); WAITVM(8); }
    else WAITVM(0);
    BAR(); SCHED0;
#pragma unroll
    for (int ks=0; ks<2; ks++){
      const int kos = (ks*32 + (lane>>4)*8) ^ rsw;
      bf16x8 a[4], b[4];
#pragma unroll
      for (int ni=0; ni<4; ni++)
        b[ni] = *(const bf16x8*)&Bl[bi*TM2*64 + (wc*64 + ni*16 + (lane&15))*64 + kos];
#pragma unroll
      for (int mi=0; mi<4; mi++)
        a[mi] = *(const bf16x8*)&Al[bi*TM2*64 + (wr*64 + mi*16 + (lane&15))*64 + kos];
#pragma unroll
      for (int mi=0; mi<4; mi++)
#pragma unroll
        for (int ni=0; ni<4; ni++)
          acc[mi][ni] = __builtin_amdgcn_mfma_f32_16x16x32_bf16(a[mi], b[ni], acc[mi][ni], 0,0,0);
    }
    BAR(); SCHED0;
  }
  const int cb = n0 + wc*64 + (lane&15);
  const int rb = wr*64 + (lane>>4)*4;
#pragma unroll
  for (int mi=0; mi<4; mi++)
#pragma unroll
    for (int j=0; j<4; j++){
      int r = rb + mi*16 + j;
      if (r < nrows){
        int slot = row0 + r;
        float wgt = sw[slot];
        float* op = gout + (size_t)slot*DIM + cb;
#pragma unroll
        for (int ni=0; ni<4; ni++)
          op[ni*16] = acc[mi][ni][j] * wgt;   // plain store, no atomics
      }
    }
}

// ---- combine: out[tok] = gout[slot0] + gout[slot1] ----
__global__ __launch_bounds__(256) void k_comb(const float* __restrict__ gout,
    const int* __restrict__ sslot, float* __restrict__ out) {
  int idx = blockIdx.x*256 + threadIdx.x;       // one float4 each
  int m = idx >> 7, c4 = (idx & 127)*4;
  int s0 = sslot[m*2], s1 = sslot[m*2+1];
  float4 x = *(const float4*)&gout[(size_t)s0*DIM + c4];
  float4 y = *(const float4*)&gout[(size_t)s1*DIM + c4];
  x.x += y.x; x.y += y.y; x.z += y.z; x.w += y.w;
  *(float4*)&out[(size_t)m*DIM + c4] = x;
}

extern "C" void kernel_launch(void* const* d_in, const int* in_sizes, int n_in,
                              void* d_out, int out_size, void* d_ws, size_t ws_size,
                              hipStream_t stream) {
  const float* tokens = (const float*)d_in[0];
  const float* disp   = (const float*)d_in[1];
  const float* comb   = (const float*)d_in[2];
  const float* Wg     = (const float*)d_in[3];
  const float* Wv     = (const float*)d_in[4];
  const float* Wo     = (const float*)d_in[5];
  const float* scales = (const float*)d_in[6];
  float* out = (float*)d_out;

  size_t off = 0;
  char* wsb = (char*)d_ws;
  auto take = [&](size_t bytes)->char* {
    char* q = wsb + off; off += (bytes + 255) & ~(size_t)255; return q;
  };
  int*   cnt   = (int*)  take(NEXP*4);
  int*   basee = (int*)  take(NEXP*4);
  int*   fillc = (int*)  take(NEXP*4);
  int*   te1   = (int*)  take(MT1*4);
  int*   trow1 = (int*)  take(MT1*4);
  int*   tn1   = (int*)  take(MT1*4);
  int*   te2   = (int*)  take(MT2*4);
  int*   trow2 = (int*)  take(MT2*4);
  int*   tn2   = (int*)  take(MT2*4);
  int*   stok  = (int*)  take((size_t)PMAX*4);
  float* sw    = (float*)take((size_t)PMAX*4);
  int*   sslot = (int*)  take((size_t)MTOK*2*4);
  bf16*  Xb    = (bf16*) take((size_t)MTOK*DIM*2);
  bf16*  WgT   = (bf16*) take((size_t)NEXP*DIM*HID*2);
  bf16*  WvT   = (bf16*) take((size_t)NEXP*DIM*HID*2);
  bf16*  WoT   = (bf16*) take((size_t)NEXP*DIM*HID*2);
  bf16*  H1    = (bf16*) take((size_t)PMAX*HID*2);
  // gout aliases WgT+WvT (64 MB, dead after gemm1; gout = 33.5 MB)
  float* gout  = (float*)WgT;
  (void)ws_size; (void)in_sizes; (void)n_in;

  hipMemsetAsync(d_ws, 0, 768, stream);
  (void)out_size;

  k_cvt_x<<<dim3((MTOK*DIM/4)/256), 256, 0, stream>>>(tokens, Xb, MTOK*DIM/4);
  k_tcvt2<<<dim3(HID/64, DIM/64, 2*NEXP), 256, 0, stream>>>(Wg, Wv, WgT, WvT, DIM, HID);
  k_tcvt2<<<dim3(DIM/64, HID/64, NEXP), 256, 0, stream>>>(Wo, Wo, WoT, WoT, HID, DIM);
  k_count<<<dim3(MTOK/256), 256, 0, stream>>>(disp, cnt);
  k_scan <<<1, 64, 0, stream>>>(cnt, basee, te1, trow1, tn1, te2, trow2, tn2);
  k_fill <<<dim3(MTOK/256), 256, 0, stream>>>(disp, comb, scales, basee, fillc, stok, sw, sslot);
  k_gemm1<<<dim3(HID/128, MT1), 512, 0, stream>>>(Xb, WgT, WvT, te1, trow1, tn1, stok, H1);
  k_gemm2<<<dim3(DIM/128, MT2), 256, 0, stream>>>(H1, WoT, te2, trow2, tn2, stok, sw, gout);
  k_comb <<<dim3(MTOK*DIM/4/256), 256, 0, stream>>>(gout, sslot, out);
}